// Round 9
// baseline (219.716 us; speedup 1.0000x reference)
//
#include <hip/hip_runtime.h>

// B=4, T=4096, C=512, H=64 causal attention head, scale=C^-0.5, fp32 I/O.
// R9: merge fused into attn (split-K last-block-merges via device-scope
// atomic counter), wt zeroes counters, f32x4 l-accumulator. 3 dispatches.

typedef __attribute__((ext_vector_type(8))) __bf16 bf16x8;
typedef __attribute__((ext_vector_type(8))) unsigned short u16x8;
typedef __attribute__((ext_vector_type(4))) float f32x4;

#define B_ 4
#define T_ 4096
#define C_ 512
#define H_ 64
#define BT (B_ * T_)

#define QSCALE (0.04419417382415922f * 1.4426950408889634f)  // C^-0.5 * log2(e)

__device__ __forceinline__ unsigned short f2bf(float f) {
    unsigned int u = __builtin_bit_cast(unsigned int, f);
    u += 0x7fffu + ((u >> 16) & 1u);
    return (unsigned short)(u >> 16);
}

__device__ __forceinline__ unsigned int pkbf(float hi, float lo) {
    return __builtin_amdgcn_perm(__builtin_bit_cast(unsigned int, hi),
                                 __builtin_bit_cast(unsigned int, lo), 0x07060302u);
}

__device__ __forceinline__ f32x4 mfma16(bf16x8 a, bf16x8 b, f32x4 c) {
    return __builtin_amdgcn_mfma_f32_16x16x32_bf16(a, b, c, 0, 0, 0);
}

// ---------------------------------------------------------------------------
// Kernel 0: Wt packed in MFMA B-fragment order; block 0 zeroes chunk counters.
// ---------------------------------------------------------------------------
__global__ __launch_bounds__(256) void wt_kernel(const float* __restrict__ Wk,
                                                 const float* __restrict__ Wq,
                                                 const float* __restrict__ Wv,
                                                 unsigned short* __restrict__ Wtp,
                                                 int* __restrict__ cnt) {
    if (blockIdx.x == 0) cnt[threadIdx.x] = 0;   // 256 = B_*64 counters
    int gid = blockIdx.x * 256 + threadIdx.x;    // 3*64*512
    int fidx = gid >> 9;
    int li = gid & 511;
    int lane = li >> 3, j = li & 7;
    int m3 = fidx / 64;
    int rem = fidx & 63;
    int nt = rem >> 4, kc = rem & 15;
    int h = nt * 16 + (lane & 15);
    int c = kc * 32 + (lane >> 4) * 8 + j;
    const float* W = (m3 == 0) ? Wk : ((m3 == 1) ? Wq : Wv);
    Wtp[gid] = f2bf(W[c * H_ + h]);
}

// ---------------------------------------------------------------------------
// Kernel 1: projections. 32 rows/block, 256 thr = 2 strips x 2 kc-halves,
// register prefetch of x and all 12 W fragments one kc ahead.
// ---------------------------------------------------------------------------
__global__ __launch_bounds__(256, 3) void proj_kernel(const float* __restrict__ x,
                                                      const unsigned short* __restrict__ Wtp,
                                                      unsigned short* __restrict__ Kf,
                                                      unsigned short* __restrict__ Qf,
                                                      unsigned short* __restrict__ Vf) {
    __shared__ __align__(16) char smem[2 * 64 * 52 * 4];   // 26624 B
    float* Mg = (float*)smem;                               // [2][64][52] f32
    unsigned short* Ks_l = (unsigned short*)smem;           // [32][68]
    unsigned short* Qs_l = Ks_l + 32 * 68;
    unsigned short* Vt_l = Qs_l + 32 * 68;                  // [64 h][34]

    const int tid = threadIdx.x;
    const int t0 = blockIdx.x * 32;
    const int wave = tid >> 6;
    const int ws = wave & 1;       // strip
    const int wh = wave >> 1;      // kc half
    const int lane = tid & 63;
    const int lane15 = lane & 15;
    const int quad = lane >> 4;

    f32x4 acc[12];
#pragma unroll
    for (int i = 0; i < 12; ++i) acc[i] = (f32x4){0.f, 0.f, 0.f, 0.f};

    const float* xrow = x + (long)(t0 + ws * 16 + lane15) * C_;
    const unsigned short* wbase = Wtp + lane * 8;

    bf16x8 wf[12];
    float4 xa0, xa1;
    {
        const int kc0 = wh * 8;
        xa0 = *(const float4*)(xrow + kc0 * 32 + quad * 8);
        xa1 = *(const float4*)(xrow + kc0 * 32 + quad * 8 + 4);
#pragma unroll
        for (int i = 0; i < 12; ++i)
            wf[i] = *(const bf16x8*)(wbase + ((i * 16 + kc0) << 9));
    }

#pragma unroll
    for (int kk = 0; kk < 8; ++kk) {
        const int kc = wh * 8 + kk;
        u16x8 t;
        t[0] = f2bf(xa0.x); t[1] = f2bf(xa0.y); t[2] = f2bf(xa0.z); t[3] = f2bf(xa0.w);
        t[4] = f2bf(xa1.x); t[5] = f2bf(xa1.y); t[6] = f2bf(xa1.z); t[7] = f2bf(xa1.w);
        bf16x8 a = __builtin_bit_cast(bf16x8, t);
        if (kk < 7) {
            xa0 = *(const float4*)(xrow + (kc + 1) * 32 + quad * 8);
            xa1 = *(const float4*)(xrow + (kc + 1) * 32 + quad * 8 + 4);
        }
#pragma unroll
        for (int i = 0; i < 12; ++i) {
            acc[i] = mfma16(a, wf[i], acc[i]);
            if (kk < 7)
                wf[i] = *(const bf16x8*)(wbase + ((i * 16 + kc + 1) << 9));
        }
    }

    // kc merge through LDS
    if (wh == 1) {
        float* mg = Mg + (ws * 64 + lane) * 52;
#pragma unroll
        for (int i = 0; i < 12; ++i) *(f32x4*)(mg + i * 4) = acc[i];
    }
    __syncthreads();
    if (wh == 0) {
        const float* mg = Mg + (ws * 64 + lane) * 52;
#pragma unroll
        for (int i = 0; i < 12; ++i) acc[i] += *(const f32x4*)(mg + i * 4);
    }
    __syncthreads();  // Mg dead

    if (wh == 0) {
#pragma unroll
        for (int nt = 0; nt < 4; ++nt) {
            int col = nt * 16 + lane15;
#pragma unroll
            for (int r = 0; r < 4; ++r) {
                int row_l = ws * 16 + quad * 4 + r;
                Ks_l[row_l * 68 + col] = f2bf(acc[0 * 4 + nt][r]);
                Qs_l[row_l * 68 + col] = f2bf(acc[1 * 4 + nt][r] * QSCALE);
                Vt_l[col * 34 + row_l] = f2bf(acc[2 * 4 + nt][r]);
            }
        }
    }
    __syncthreads();

    const int b = t0 >> 12;
    const int tloc = t0 & 4095;
    const int st = wave >> 1, kk = wave & 1;
    const long gs = (long)(b * 256 + (tloc >> 4) + st);
    bf16x8 kv = *(const bf16x8*)&Ks_l[(st * 16 + lane15) * 68 + kk * 32 + quad * 8];
    *(bf16x8*)&Kf[(gs * 2 + kk) * 512 + lane * 8] = kv;
    bf16x8 qv = *(const bf16x8*)&Qs_l[(st * 16 + lane15) * 68 + kk * 32 + quad * 8];
    *(bf16x8*)&Qf[(gs * 2 + kk) * 512 + lane * 8] = qv;
    const int hf = wave;
    const int vkk = (tloc >> 5) & 1;
    bf16x8 vv = *(const bf16x8*)&Vt_l[(hf * 16 + lane15) * 34 + quad * 8];
    const long sb = (long)(b * 64 + (tloc >> 6));
    *(bf16x8*)&Vf[(sb * 8 + hf * 2 + vkk) * 512 + lane * 8] = vv;
}

// ---------------------------------------------------------------------------
// Kernel 2: attention + fused split-K merge. Block = (b, qt, chunk<=16 tiles).
// Last chunk-block to finish a (b,qt) merges partials and writes out.
// ---------------------------------------------------------------------------
#define PSP 72

__global__ __launch_bounds__(256, 3) void attn_kernel(const unsigned short* __restrict__ Qf,
                                                      const unsigned short* __restrict__ Kf,
                                                      const unsigned short* __restrict__ Vf,
                                                      float* __restrict__ Op,
                                                      float* __restrict__ lp,
                                                      int* __restrict__ cnt,
                                                      float* __restrict__ out) {
    __shared__ __align__(16) unsigned short Ps[4 * 16 * PSP];  // 9216 B
    __shared__ int do_merge;

    const int tid = threadIdx.x;
    const int wave = tid >> 6;
    const int lane = tid & 63;
    const int lane15 = lane & 15;
    const int quad = lane >> 4;
    const int b = blockIdx.y;

    // longest chunks first
    const int z = 159 - blockIdx.x;
    int g, zb;
    if (z < 16)      { g = 0; zb = 0; }
    else if (z < 48) { g = 1; zb = 16; }
    else if (z < 96) { g = 2; zb = 48; }
    else             { g = 3; zb = 96; }
    const int idx = z - zb;
    const int qt = g * 16 + idx / (g + 1);
    const int chunk = idx % (g + 1);
    const int ntt = min(16, qt + 1 - chunk * 16);
    const int t0k = chunk * 16;

    const long gs_q = (long)(b * 256 + qt * 4 + wave);
    const unsigned short* qb = Qf + gs_q * 1024 + lane * 8;
    const bf16x8 qf0 = *(const bf16x8*)qb;
    const bf16x8 qf1 = *(const bf16x8*)(qb + 512);

    f32x4 o_acc[4];
    f32x4 l_vec = (f32x4){0.f, 0.f, 0.f, 0.f};
#pragma unroll
    for (int hf = 0; hf < 4; ++hf) o_acc[hf] = (f32x4){0.f, 0.f, 0.f, 0.f};

    unsigned short* pw = Ps + wave * 16 * PSP;

    // preload tile 0
    bf16x8 kf[8], vf[8];
    {
        const unsigned short* kb = Kf + (long)(b * 256 + t0k * 4) * 1024 + lane * 8;
        const unsigned short* vb = Vf + (long)(b * 64 + t0k) * 4096 + lane * 8;
#pragma unroll
        for (int ct = 0; ct < 4; ++ct) {
            kf[ct * 2 + 0] = *(const bf16x8*)(kb + ct * 1024);
            kf[ct * 2 + 1] = *(const bf16x8*)(kb + ct * 1024 + 512);
        }
#pragma unroll
        for (int f = 0; f < 8; ++f) vf[f] = *(const bf16x8*)(vb + f * 512);
    }

    for (int t = 0; t < ntt; ++t) {
        const int kc = t0k + t;
        const bool more = (t + 1 < ntt);
        const unsigned short* kbn = Kf + (long)(b * 256 + (kc + 1) * 4) * 1024 + lane * 8;
        const unsigned short* vbn = Vf + (long)(b * 64 + kc + 1) * 4096 + lane * 8;

        // S^T = K Q^T : (s = kc*64 + ct*16 + quad*4 + r, q = lane15)
        f32x4 st[4];
#pragma unroll
        for (int ct = 0; ct < 4; ++ct) {
            f32x4 zz = (f32x4){0.f, 0.f, 0.f, 0.f};
            zz = mfma16(kf[ct * 2 + 0], qf0, zz);
            zz = mfma16(kf[ct * 2 + 1], qf1, zz);
            st[ct] = zz;
        }

        if (more) {
#pragma unroll
            for (int ct = 0; ct < 4; ++ct) {
                kf[ct * 2 + 0] = *(const bf16x8*)(kbn + ct * 1024);
                kf[ct * 2 + 1] = *(const bf16x8*)(kbn + ct * 1024 + 512);
            }
        }

        if (kc == qt) {
            const int qg = wave * 16 + lane15;
#pragma unroll
            for (int ct = 0; ct < 4; ++ct) {
                const int sb = ct * 16 + quad * 4;
#pragma unroll
                for (int r = 0; r < 4; ++r)
                    if (sb + r > qg) st[ct][r] = -3.0e38f;
            }
        }

        // fixed-max softmax (exp2 domain); vector l accumulator (depth 4/tile)
#pragma unroll
        for (int ct = 0; ct < 4; ++ct) {
#pragma unroll
            for (int r = 0; r < 4; ++r)
                st[ct][r] = __builtin_amdgcn_exp2f(st[ct][r]);
            l_vec += st[ct];
        }

        // pack P (s-contiguous in regs) -> LDS [q][s]
#pragma unroll
        for (int ct = 0; ct < 4; ++ct) {
            unsigned int w0 = pkbf(st[ct][1], st[ct][0]);
            unsigned int w1 = pkbf(st[ct][3], st[ct][2]);
            *(uint2*)&pw[lane15 * PSP + ct * 16 + quad * 4] = make_uint2(w0, w1);
        }

        bf16x8 pa0 = *(const bf16x8*)&pw[lane15 * PSP + quad * 8];
        bf16x8 pa1 = *(const bf16x8*)&pw[lane15 * PSP + 32 + quad * 8];
#pragma unroll
        for (int hf = 0; hf < 4; ++hf) {
            o_acc[hf] = mfma16(pa0, vf[hf * 2 + 0], o_acc[hf]);
            o_acc[hf] = mfma16(pa1, vf[hf * 2 + 1], o_acc[hf]);
        }

        if (more) {
#pragma unroll
            for (int f = 0; f < 8; ++f) vf[f] = *(const bf16x8*)(vbn + f * 512);
        }
    }

    // l: fold vector lanes then sum over the 4 quads holding each q
    float l_acc = (l_vec[0] + l_vec[1]) + (l_vec[2] + l_vec[3]);
    l_acc += __shfl_xor(l_acc, 16);
    l_acc += __shfl_xor(l_acc, 32);

    if ((qt >> 4) == 0) {
        // single-chunk q tile: normalize and write out directly
        float linv[4];
#pragma unroll
        for (int r = 0; r < 4; ++r) linv[r] = 1.0f / __shfl(l_acc, quad * 4 + r);
        float* o = out + ((long)b * T_ + qt * 64 + wave * 16) * H_;
#pragma unroll
        for (int hf = 0; hf < 4; ++hf)
#pragma unroll
            for (int r = 0; r < 4; ++r)
                o[(quad * 4 + r) * H_ + hf * 16 + lane15] = o_acc[hf][r] * linv[r];
    } else {
        const int nc = 1 + (qt >> 4);
        const long pbase = ((long)(b * 64 + qt) * 4 + chunk) * 64;
        if (quad == 0) lp[pbase + wave * 16 + lane15] = l_acc;
        float* op = Op + (pbase + wave * 16) * 64;
#pragma unroll
        for (int hf = 0; hf < 4; ++hf)
#pragma unroll
            for (int r = 0; r < 4; ++r)
                op[(quad * 4 + r) * 64 + hf * 16 + lane15] = o_acc[hf][r];

        __threadfence();  // release partials device-wide
        if (tid == 0) {
            int old = atomicAdd(&cnt[b * 64 + qt], 1);
            do_merge = (old == nc - 1) ? 1 : 0;
        }
        __syncthreads();

        if (do_merge) {
            __threadfence();  // acquire
            const int row = tid >> 2;
            const int seg = (tid & 3) << 4;
            const long base = (long)(b * 64 + qt) * 4;
            float l = 0.f;
            f32x4 a[4];
#pragma unroll
            for (int j = 0; j < 4; ++j) a[j] = (f32x4){0.f, 0.f, 0.f, 0.f};
            for (int c = 0; c < nc; ++c) {
                l += lp[(base + c) * 64 + row];
                const float* opr = Op + ((base + c) * 64 + row) * 64 + seg;
#pragma unroll
                for (int j = 0; j < 4; ++j) a[j] += *(const f32x4*)(opr + j * 4);
            }
            const float inv = 1.0f / l;
            float* o = out + ((long)b * T_ + qt * 64 + row) * H_ + seg;
#pragma unroll
            for (int j = 0; j < 4; ++j) *(f32x4*)(o + j * 4) = a[j] * inv;
        }
    }
}

// ---------------------------------------------------------------------------
extern "C" void kernel_launch(void* const* d_in, const int* in_sizes, int n_in,
                              void* d_out, int out_size, void* d_ws, size_t ws_size,
                              hipStream_t stream) {
    const float* x  = (const float*)d_in[0];
    const float* Wk = (const float*)d_in[1];
    const float* Wq = (const float*)d_in[2];
    const float* Wv = (const float*)d_in[3];
    float* out = (float*)d_out;

    char* ws = (char*)d_ws;
    unsigned short* Kf  = (unsigned short*)(ws);                // 2 MB
    unsigned short* Qf  = (unsigned short*)(ws + (2u << 20));   // 2 MB
    unsigned short* Vf  = (unsigned short*)(ws + (4u << 20));   // 2 MB
    unsigned short* Wtp = (unsigned short*)(ws + (6u << 20));   // 192 KB
    int* cnt = (int*)(ws + (7u << 20));                         // 1 KB
    float* Op = (float*)(ws + (8u << 20));                      // 16 MB
    float* lp = (float*)(ws + (24u << 20));                     // 256 KB

    wt_kernel<<<384, 256, 0, stream>>>(Wk, Wq, Wv, Wtp, cnt);
    proj_kernel<<<BT / 32, 256, 0, stream>>>(x, Wtp, Kf, Qf, Vf);
    attn_kernel<<<dim3(160, B_), 256, 0, stream>>>(Qf, Kf, Vf, Op, lp, cnt, out);
}

// Round 10
// 120.649 us; speedup vs baseline: 1.8211x; 1.8211x over previous
//
#include <hip/hip_runtime.h>

// B=4, T=4096, C=512, H=64 causal attention head, scale=C^-0.5, fp32 I/O.
// R10: revert R9's fence/atomic fused merge (agent fences = per-block L2
// writeback/inv on gfx950 -> 100us regression). Separate merge kernel.
// Chunk 16->8 tiles: 1152 attn blocks (4.5/CU), critical path halved.

typedef __attribute__((ext_vector_type(8))) __bf16 bf16x8;
typedef __attribute__((ext_vector_type(8))) unsigned short u16x8;
typedef __attribute__((ext_vector_type(4))) float f32x4;

#define B_ 4
#define T_ 4096
#define C_ 512
#define H_ 64
#define BT (B_ * T_)

#define QSCALE (0.04419417382415922f * 1.4426950408889634f)  // C^-0.5 * log2(e)

__device__ __forceinline__ unsigned short f2bf(float f) {
    unsigned int u = __builtin_bit_cast(unsigned int, f);
    u += 0x7fffu + ((u >> 16) & 1u);
    return (unsigned short)(u >> 16);
}

__device__ __forceinline__ unsigned int pkbf(float hi, float lo) {
    return __builtin_amdgcn_perm(__builtin_bit_cast(unsigned int, hi),
                                 __builtin_bit_cast(unsigned int, lo), 0x07060302u);
}

__device__ __forceinline__ f32x4 mfma16(bf16x8 a, bf16x8 b, f32x4 c) {
    return __builtin_amdgcn_mfma_f32_16x16x32_bf16(a, b, c, 0, 0, 0);
}

// ---------------------------------------------------------------------------
// Kernel 0: Wt packed in MFMA B-fragment order.
// ---------------------------------------------------------------------------
__global__ __launch_bounds__(256) void wt_kernel(const float* __restrict__ Wk,
                                                 const float* __restrict__ Wq,
                                                 const float* __restrict__ Wv,
                                                 unsigned short* __restrict__ Wtp) {
    int gid = blockIdx.x * 256 + threadIdx.x;  // 3*64*512
    int fidx = gid >> 9;
    int li = gid & 511;
    int lane = li >> 3, j = li & 7;
    int m3 = fidx / 64;
    int rem = fidx & 63;
    int nt = rem >> 4, kc = rem & 15;
    int h = nt * 16 + (lane & 15);
    int c = kc * 32 + (lane >> 4) * 8 + j;
    const float* W = (m3 == 0) ? Wk : ((m3 == 1) ? Wq : Wv);
    Wtp[gid] = f2bf(W[c * H_ + h]);
}

// ---------------------------------------------------------------------------
// Kernel 1: projections. 32 rows/block, 256 thr = 2 strips x 2 kc-halves,
// register prefetch of x and all 12 W fragments one kc ahead.
// ---------------------------------------------------------------------------
__global__ __launch_bounds__(256, 3) void proj_kernel(const float* __restrict__ x,
                                                      const unsigned short* __restrict__ Wtp,
                                                      unsigned short* __restrict__ Kf,
                                                      unsigned short* __restrict__ Qf,
                                                      unsigned short* __restrict__ Vf) {
    __shared__ __align__(16) char smem[2 * 64 * 52 * 4];   // 26624 B
    float* Mg = (float*)smem;                               // [2][64][52] f32
    unsigned short* Ks_l = (unsigned short*)smem;           // [32][68]
    unsigned short* Qs_l = Ks_l + 32 * 68;
    unsigned short* Vt_l = Qs_l + 32 * 68;                  // [64 h][34]

    const int tid = threadIdx.x;
    const int t0 = blockIdx.x * 32;
    const int wave = tid >> 6;
    const int ws = wave & 1;       // strip
    const int wh = wave >> 1;      // kc half
    const int lane = tid & 63;
    const int lane15 = lane & 15;
    const int quad = lane >> 4;

    f32x4 acc[12];
#pragma unroll
    for (int i = 0; i < 12; ++i) acc[i] = (f32x4){0.f, 0.f, 0.f, 0.f};

    const float* xrow = x + (long)(t0 + ws * 16 + lane15) * C_;
    const unsigned short* wbase = Wtp + lane * 8;

    bf16x8 wf[12];
    float4 xa0, xa1;
    {
        const int kc0 = wh * 8;
        xa0 = *(const float4*)(xrow + kc0 * 32 + quad * 8);
        xa1 = *(const float4*)(xrow + kc0 * 32 + quad * 8 + 4);
#pragma unroll
        for (int i = 0; i < 12; ++i)
            wf[i] = *(const bf16x8*)(wbase + ((i * 16 + kc0) << 9));
    }

#pragma unroll
    for (int kk = 0; kk < 8; ++kk) {
        const int kc = wh * 8 + kk;
        u16x8 t;
        t[0] = f2bf(xa0.x); t[1] = f2bf(xa0.y); t[2] = f2bf(xa0.z); t[3] = f2bf(xa0.w);
        t[4] = f2bf(xa1.x); t[5] = f2bf(xa1.y); t[6] = f2bf(xa1.z); t[7] = f2bf(xa1.w);
        bf16x8 a = __builtin_bit_cast(bf16x8, t);
        if (kk < 7) {
            xa0 = *(const float4*)(xrow + (kc + 1) * 32 + quad * 8);
            xa1 = *(const float4*)(xrow + (kc + 1) * 32 + quad * 8 + 4);
        }
#pragma unroll
        for (int i = 0; i < 12; ++i) {
            acc[i] = mfma16(a, wf[i], acc[i]);
            if (kk < 7)
                wf[i] = *(const bf16x8*)(wbase + ((i * 16 + kc + 1) << 9));
        }
    }

    // kc merge through LDS
    if (wh == 1) {
        float* mg = Mg + (ws * 64 + lane) * 52;
#pragma unroll
        for (int i = 0; i < 12; ++i) *(f32x4*)(mg + i * 4) = acc[i];
    }
    __syncthreads();
    if (wh == 0) {
        const float* mg = Mg + (ws * 64 + lane) * 52;
#pragma unroll
        for (int i = 0; i < 12; ++i) acc[i] += *(const f32x4*)(mg + i * 4);
    }
    __syncthreads();  // Mg dead

    if (wh == 0) {
#pragma unroll
        for (int nt = 0; nt < 4; ++nt) {
            int col = nt * 16 + lane15;
#pragma unroll
            for (int r = 0; r < 4; ++r) {
                int row_l = ws * 16 + quad * 4 + r;
                Ks_l[row_l * 68 + col] = f2bf(acc[0 * 4 + nt][r]);
                Qs_l[row_l * 68 + col] = f2bf(acc[1 * 4 + nt][r] * QSCALE);
                Vt_l[col * 34 + row_l] = f2bf(acc[2 * 4 + nt][r]);
            }
        }
    }
    __syncthreads();

    const int b = t0 >> 12;
    const int tloc = t0 & 4095;
    const int st = wave >> 1, kk = wave & 1;
    const long gs = (long)(b * 256 + (tloc >> 4) + st);
    bf16x8 kv = *(const bf16x8*)&Ks_l[(st * 16 + lane15) * 68 + kk * 32 + quad * 8];
    *(bf16x8*)&Kf[(gs * 2 + kk) * 512 + lane * 8] = kv;
    bf16x8 qv = *(const bf16x8*)&Qs_l[(st * 16 + lane15) * 68 + kk * 32 + quad * 8];
    *(bf16x8*)&Qf[(gs * 2 + kk) * 512 + lane * 8] = qv;
    const int hf = wave;
    const int vkk = (tloc >> 5) & 1;
    bf16x8 vv = *(const bf16x8*)&Vt_l[(hf * 16 + lane15) * 34 + quad * 8];
    const long sb = (long)(b * 64 + (tloc >> 6));
    *(bf16x8*)&Vf[(sb * 8 + hf * 2 + vkk) * 512 + lane * 8] = vv;
}

// ---------------------------------------------------------------------------
// Kernel 2: attention. Block = (b, qt, chunk of <=8 K tiles). 4 waves split
// Q; shared K/V tiles; register pipelined. qt<8 writes out directly.
// ---------------------------------------------------------------------------
#define PSP 72

__global__ __launch_bounds__(256, 3) void attn_kernel(const unsigned short* __restrict__ Qf,
                                                      const unsigned short* __restrict__ Kf,
                                                      const unsigned short* __restrict__ Vf,
                                                      float* __restrict__ Op,
                                                      float* __restrict__ lp,
                                                      float* __restrict__ out) {
    __shared__ __align__(16) unsigned short Ps[4 * 16 * PSP];  // 9216 B

    const int tid = threadIdx.x;
    const int wave = tid >> 6;
    const int lane = tid & 63;
    const int lane15 = lane & 15;
    const int quad = lane >> 4;
    const int b = blockIdx.y;

    // longest chunks first. Group g = qt>>3 has 8 qt values x (g+1) chunks,
    // so group base zb = 4g(g+1); 288 blocks per batch.
    const int z = 287 - blockIdx.x;
    int g = (int)((__builtin_sqrtf((float)z + 1.0f) - 1.0f) * 0.5f);
    while (4 * (g + 1) * (g + 2) <= z) ++g;
    while (4 * g * (g + 1) > z) --g;
    const int idx = z - 4 * g * (g + 1);
    const int qt = g * 8 + idx / (g + 1);
    const int chunk = idx % (g + 1);
    const int ntt = min(8, qt + 1 - chunk * 8);
    const int t0k = chunk * 8;

    const long gs_q = (long)(b * 256 + qt * 4 + wave);
    const unsigned short* qb = Qf + gs_q * 1024 + lane * 8;
    const bf16x8 qf0 = *(const bf16x8*)qb;
    const bf16x8 qf1 = *(const bf16x8*)(qb + 512);

    f32x4 o_acc[4];
    f32x4 l_vec = (f32x4){0.f, 0.f, 0.f, 0.f};
#pragma unroll
    for (int hf = 0; hf < 4; ++hf) o_acc[hf] = (f32x4){0.f, 0.f, 0.f, 0.f};

    unsigned short* pw = Ps + wave * 16 * PSP;

    // preload tile 0
    bf16x8 kf[8], vf[8];
    {
        const unsigned short* kb = Kf + (long)(b * 256 + t0k * 4) * 1024 + lane * 8;
        const unsigned short* vb = Vf + (long)(b * 64 + t0k) * 4096 + lane * 8;
#pragma unroll
        for (int ct = 0; ct < 4; ++ct) {
            kf[ct * 2 + 0] = *(const bf16x8*)(kb + ct * 1024);
            kf[ct * 2 + 1] = *(const bf16x8*)(kb + ct * 1024 + 512);
        }
#pragma unroll
        for (int f = 0; f < 8; ++f) vf[f] = *(const bf16x8*)(vb + f * 512);
    }

    for (int t = 0; t < ntt; ++t) {
        const int kc = t0k + t;
        const bool more = (t + 1 < ntt);
        const unsigned short* kbn = Kf + (long)(b * 256 + (kc + 1) * 4) * 1024 + lane * 8;
        const unsigned short* vbn = Vf + (long)(b * 64 + kc + 1) * 4096 + lane * 8;

        // S^T = K Q^T : (s = kc*64 + ct*16 + quad*4 + r, q = lane15)
        f32x4 st[4];
#pragma unroll
        for (int ct = 0; ct < 4; ++ct) {
            f32x4 zz = (f32x4){0.f, 0.f, 0.f, 0.f};
            zz = mfma16(kf[ct * 2 + 0], qf0, zz);
            zz = mfma16(kf[ct * 2 + 1], qf1, zz);
            st[ct] = zz;
        }

        if (more) {
#pragma unroll
            for (int ct = 0; ct < 4; ++ct) {
                kf[ct * 2 + 0] = *(const bf16x8*)(kbn + ct * 1024);
                kf[ct * 2 + 1] = *(const bf16x8*)(kbn + ct * 1024 + 512);
            }
        }

        if (kc == qt) {
            const int qg = wave * 16 + lane15;
#pragma unroll
            for (int ct = 0; ct < 4; ++ct) {
                const int sb = ct * 16 + quad * 4;
#pragma unroll
                for (int r = 0; r < 4; ++r)
                    if (sb + r > qg) st[ct][r] = -3.0e38f;
            }
        }

        // fixed-max softmax (exp2 domain); vector l accumulator
#pragma unroll
        for (int ct = 0; ct < 4; ++ct) {
#pragma unroll
            for (int r = 0; r < 4; ++r)
                st[ct][r] = __builtin_amdgcn_exp2f(st[ct][r]);
            l_vec += st[ct];
        }

        // pack P (s-contiguous in regs) -> LDS [q][s]
#pragma unroll
        for (int ct = 0; ct < 4; ++ct) {
            unsigned int w0 = pkbf(st[ct][1], st[ct][0]);
            unsigned int w1 = pkbf(st[ct][3], st[ct][2]);
            *(uint2*)&pw[lane15 * PSP + ct * 16 + quad * 4] = make_uint2(w0, w1);
        }

        bf16x8 pa0 = *(const bf16x8*)&pw[lane15 * PSP + quad * 8];
        bf16x8 pa1 = *(const bf16x8*)&pw[lane15 * PSP + 32 + quad * 8];
#pragma unroll
        for (int hf = 0; hf < 4; ++hf) {
            o_acc[hf] = mfma16(pa0, vf[hf * 2 + 0], o_acc[hf]);
            o_acc[hf] = mfma16(pa1, vf[hf * 2 + 1], o_acc[hf]);
        }

        if (more) {
#pragma unroll
            for (int f = 0; f < 8; ++f) vf[f] = *(const bf16x8*)(vbn + f * 512);
        }
    }

    // l: fold vector lanes then sum over the 4 quads holding each q
    float l_acc = (l_vec[0] + l_vec[1]) + (l_vec[2] + l_vec[3]);
    l_acc += __shfl_xor(l_acc, 16);
    l_acc += __shfl_xor(l_acc, 32);

    if ((qt >> 3) == 0) {
        // single-chunk q tile: normalize and write out directly
        float linv[4];
#pragma unroll
        for (int r = 0; r < 4; ++r) linv[r] = 1.0f / __shfl(l_acc, quad * 4 + r);
        float* o = out + ((long)b * T_ + qt * 64 + wave * 16) * H_;
#pragma unroll
        for (int hf = 0; hf < 4; ++hf)
#pragma unroll
            for (int r = 0; r < 4; ++r)
                o[(quad * 4 + r) * H_ + hf * 16 + lane15] = o_acc[hf][r] * linv[r];
    } else {
        const long pbase = ((long)(b * 64 + qt) * 8 + chunk) * 64;
        if (quad == 0) lp[pbase + wave * 16 + lane15] = l_acc;
        float* op = Op + (pbase + wave * 16) * 64;
#pragma unroll
        for (int hf = 0; hf < 4; ++hf)
#pragma unroll
            for (int r = 0; r < 4; ++r)
                op[(quad * 4 + r) * 64 + hf * 16 + lane15] = o_acc[hf][r];
    }
}

// ---------------------------------------------------------------------------
// Kernel 3: merge chunk partials for qt in [8, 64). Block = (qt-8, b).
// ---------------------------------------------------------------------------
__global__ __launch_bounds__(256) void merge_kernel(const float* __restrict__ Op,
                                                    const float* __restrict__ lp,
                                                    float* __restrict__ out) {
    const int qt = 8 + blockIdx.x;
    const int b = blockIdx.y;
    const int nc = 1 + (qt >> 3);   // 2..8
    const int tid = threadIdx.x;
    const int row = tid >> 2;
    const int seg = (tid & 3) << 4;

    const long base = (long)(b * 64 + qt) * 8;
    float l = 0.f;
    f32x4 a[4];
#pragma unroll
    for (int j = 0; j < 4; ++j) a[j] = (f32x4){0.f, 0.f, 0.f, 0.f};

    for (int c = 0; c < nc; ++c) {
        l += lp[(base + c) * 64 + row];
        const float* op = Op + ((base + c) * 64 + row) * 64 + seg;
#pragma unroll
        for (int j = 0; j < 4; ++j) a[j] += *(const f32x4*)(op + j * 4);
    }
    const float inv = 1.0f / l;
    float* o = out + ((long)b * T_ + qt * 64 + row) * H_ + seg;
#pragma unroll
    for (int j = 0; j < 4; ++j) *(f32x4*)(o + j * 4) = a[j] * inv;
}

// ---------------------------------------------------------------------------
extern "C" void kernel_launch(void* const* d_in, const int* in_sizes, int n_in,
                              void* d_out, int out_size, void* d_ws, size_t ws_size,
                              hipStream_t stream) {
    const float* x  = (const float*)d_in[0];
    const float* Wk = (const float*)d_in[1];
    const float* Wq = (const float*)d_in[2];
    const float* Wv = (const float*)d_in[3];
    float* out = (float*)d_out;

    char* ws = (char*)d_ws;
    unsigned short* Kf  = (unsigned short*)(ws);                // 2 MB
    unsigned short* Qf  = (unsigned short*)(ws + (2u << 20));   // 2 MB
    unsigned short* Vf  = (unsigned short*)(ws + (4u << 20));   // 2 MB
    unsigned short* Wtp = (unsigned short*)(ws + (6u << 20));   // 192 KB
    float* Op = (float*)(ws + (8u << 20));                      // 32 MB
    float* lp = (float*)(ws + (40u << 20));                     // 512 KB

    wt_kernel<<<384, 256, 0, stream>>>(Wk, Wq, Wv, Wtp);
    proj_kernel<<<BT / 32, 256, 0, stream>>>(x, Wtp, Kf, Qf, Vf);
    attn_kernel<<<dim3(288, B_), 256, 0, stream>>>(Qf, Kf, Vf, Op, lp, out);
    merge_kernel<<<dim3(56, B_), 256, 0, stream>>>(Op, lp, out);
}

// Round 11
// 118.686 us; speedup vs baseline: 1.8512x; 1.0165x over previous
//
#include <hip/hip_runtime.h>

// B=4, T=4096, C=512, H=64 causal attention head, scale=C^-0.5, fp32 I/O.
// R11 = R10 + (a) bf16 attention partials (halves Op round-trip traffic),
// (b) double-buffered P scratch + unroll-2 tile loop for cross-tile overlap.

typedef __attribute__((ext_vector_type(8))) __bf16 bf16x8;
typedef __attribute__((ext_vector_type(8))) unsigned short u16x8;
typedef __attribute__((ext_vector_type(4))) float f32x4;

#define B_ 4
#define T_ 4096
#define C_ 512
#define H_ 64
#define BT (B_ * T_)

#define QSCALE (0.04419417382415922f * 1.4426950408889634f)  // C^-0.5 * log2(e)

__device__ __forceinline__ unsigned short f2bf(float f) {
    unsigned int u = __builtin_bit_cast(unsigned int, f);
    u += 0x7fffu + ((u >> 16) & 1u);
    return (unsigned short)(u >> 16);
}

__device__ __forceinline__ unsigned int pkbf(float hi, float lo) {
    return __builtin_amdgcn_perm(__builtin_bit_cast(unsigned int, hi),
                                 __builtin_bit_cast(unsigned int, lo), 0x07060302u);
}

__device__ __forceinline__ float bf2f_lo(unsigned int u) {
    return __builtin_bit_cast(float, u << 16);
}
__device__ __forceinline__ float bf2f_hi(unsigned int u) {
    return __builtin_bit_cast(float, u & 0xffff0000u);
}

__device__ __forceinline__ f32x4 mfma16(bf16x8 a, bf16x8 b, f32x4 c) {
    return __builtin_amdgcn_mfma_f32_16x16x32_bf16(a, b, c, 0, 0, 0);
}

// ---------------------------------------------------------------------------
// Kernel 0: Wt packed in MFMA B-fragment order.
// ---------------------------------------------------------------------------
__global__ __launch_bounds__(256) void wt_kernel(const float* __restrict__ Wk,
                                                 const float* __restrict__ Wq,
                                                 const float* __restrict__ Wv,
                                                 unsigned short* __restrict__ Wtp) {
    int gid = blockIdx.x * 256 + threadIdx.x;  // 3*64*512
    int fidx = gid >> 9;
    int li = gid & 511;
    int lane = li >> 3, j = li & 7;
    int m3 = fidx / 64;
    int rem = fidx & 63;
    int nt = rem >> 4, kc = rem & 15;
    int h = nt * 16 + (lane & 15);
    int c = kc * 32 + (lane >> 4) * 8 + j;
    const float* W = (m3 == 0) ? Wk : ((m3 == 1) ? Wq : Wv);
    Wtp[gid] = f2bf(W[c * H_ + h]);
}

// ---------------------------------------------------------------------------
// Kernel 1: projections. 32 rows/block, 256 thr = 2 strips x 2 kc-halves,
// register prefetch of x and all 12 W fragments one kc ahead.
// ---------------------------------------------------------------------------
__global__ __launch_bounds__(256, 3) void proj_kernel(const float* __restrict__ x,
                                                      const unsigned short* __restrict__ Wtp,
                                                      unsigned short* __restrict__ Kf,
                                                      unsigned short* __restrict__ Qf,
                                                      unsigned short* __restrict__ Vf) {
    __shared__ __align__(16) char smem[2 * 64 * 52 * 4];   // 26624 B
    float* Mg = (float*)smem;                               // [2][64][52] f32
    unsigned short* Ks_l = (unsigned short*)smem;           // [32][68]
    unsigned short* Qs_l = Ks_l + 32 * 68;
    unsigned short* Vt_l = Qs_l + 32 * 68;                  // [64 h][34]

    const int tid = threadIdx.x;
    const int t0 = blockIdx.x * 32;
    const int wave = tid >> 6;
    const int ws = wave & 1;       // strip
    const int wh = wave >> 1;      // kc half
    const int lane = tid & 63;
    const int lane15 = lane & 15;
    const int quad = lane >> 4;

    f32x4 acc[12];
#pragma unroll
    for (int i = 0; i < 12; ++i) acc[i] = (f32x4){0.f, 0.f, 0.f, 0.f};

    const float* xrow = x + (long)(t0 + ws * 16 + lane15) * C_;
    const unsigned short* wbase = Wtp + lane * 8;

    bf16x8 wf[12];
    float4 xa0, xa1;
    {
        const int kc0 = wh * 8;
        xa0 = *(const float4*)(xrow + kc0 * 32 + quad * 8);
        xa1 = *(const float4*)(xrow + kc0 * 32 + quad * 8 + 4);
#pragma unroll
        for (int i = 0; i < 12; ++i)
            wf[i] = *(const bf16x8*)(wbase + ((i * 16 + kc0) << 9));
    }

#pragma unroll
    for (int kk = 0; kk < 8; ++kk) {
        const int kc = wh * 8 + kk;
        u16x8 t;
        t[0] = f2bf(xa0.x); t[1] = f2bf(xa0.y); t[2] = f2bf(xa0.z); t[3] = f2bf(xa0.w);
        t[4] = f2bf(xa1.x); t[5] = f2bf(xa1.y); t[6] = f2bf(xa1.z); t[7] = f2bf(xa1.w);
        bf16x8 a = __builtin_bit_cast(bf16x8, t);
        if (kk < 7) {
            xa0 = *(const float4*)(xrow + (kc + 1) * 32 + quad * 8);
            xa1 = *(const float4*)(xrow + (kc + 1) * 32 + quad * 8 + 4);
        }
#pragma unroll
        for (int i = 0; i < 12; ++i) {
            acc[i] = mfma16(a, wf[i], acc[i]);
            if (kk < 7)
                wf[i] = *(const bf16x8*)(wbase + ((i * 16 + kc + 1) << 9));
        }
    }

    // kc merge through LDS
    if (wh == 1) {
        float* mg = Mg + (ws * 64 + lane) * 52;
#pragma unroll
        for (int i = 0; i < 12; ++i) *(f32x4*)(mg + i * 4) = acc[i];
    }
    __syncthreads();
    if (wh == 0) {
        const float* mg = Mg + (ws * 64 + lane) * 52;
#pragma unroll
        for (int i = 0; i < 12; ++i) acc[i] += *(const f32x4*)(mg + i * 4);
    }
    __syncthreads();  // Mg dead

    if (wh == 0) {
#pragma unroll
        for (int nt = 0; nt < 4; ++nt) {
            int col = nt * 16 + lane15;
#pragma unroll
            for (int r = 0; r < 4; ++r) {
                int row_l = ws * 16 + quad * 4 + r;
                Ks_l[row_l * 68 + col] = f2bf(acc[0 * 4 + nt][r]);
                Qs_l[row_l * 68 + col] = f2bf(acc[1 * 4 + nt][r] * QSCALE);
                Vt_l[col * 34 + row_l] = f2bf(acc[2 * 4 + nt][r]);
            }
        }
    }
    __syncthreads();

    const int b = t0 >> 12;
    const int tloc = t0 & 4095;
    const int st = wave >> 1, kk = wave & 1;
    const long gs = (long)(b * 256 + (tloc >> 4) + st);
    bf16x8 kv = *(const bf16x8*)&Ks_l[(st * 16 + lane15) * 68 + kk * 32 + quad * 8];
    *(bf16x8*)&Kf[(gs * 2 + kk) * 512 + lane * 8] = kv;
    bf16x8 qv = *(const bf16x8*)&Qs_l[(st * 16 + lane15) * 68 + kk * 32 + quad * 8];
    *(bf16x8*)&Qf[(gs * 2 + kk) * 512 + lane * 8] = qv;
    const int hf = wave;
    const int vkk = (tloc >> 5) & 1;
    bf16x8 vv = *(const bf16x8*)&Vt_l[(hf * 16 + lane15) * 34 + quad * 8];
    const long sb = (long)(b * 64 + (tloc >> 6));
    *(bf16x8*)&Vf[(sb * 8 + hf * 2 + vkk) * 512 + lane * 8] = vv;
}

// ---------------------------------------------------------------------------
// Kernel 2: attention. Block = (b, qt, chunk of <=8 K tiles). 4 waves split
// Q; shared K/V tiles; register pipelined; double-buffered P scratch.
// qt<8 writes out directly; else bf16 partials to Opb + fp32 l to lp.
// ---------------------------------------------------------------------------
#define PSP 72

__global__ __launch_bounds__(256, 3) void attn_kernel(const unsigned short* __restrict__ Qf,
                                                      const unsigned short* __restrict__ Kf,
                                                      const unsigned short* __restrict__ Vf,
                                                      unsigned short* __restrict__ Opb,
                                                      float* __restrict__ lp,
                                                      float* __restrict__ out) {
    __shared__ __align__(16) unsigned short Ps[8 * 16 * PSP];  // 18432 B (2 buf/wave)

    const int tid = threadIdx.x;
    const int wave = tid >> 6;
    const int lane = tid & 63;
    const int lane15 = lane & 15;
    const int quad = lane >> 4;
    const int b = blockIdx.y;

    // longest chunks first. Group g = qt>>3 has 8 qt values x (g+1) chunks,
    // group base zb = 4g(g+1); 288 blocks per batch.
    const int z = 287 - blockIdx.x;
    int g = (int)((__builtin_sqrtf((float)z + 1.0f) - 1.0f) * 0.5f);
    while (4 * (g + 1) * (g + 2) <= z) ++g;
    while (4 * g * (g + 1) > z) --g;
    const int idx = z - 4 * g * (g + 1);
    const int qt = g * 8 + idx / (g + 1);
    const int chunk = idx % (g + 1);
    const int ntt = min(8, qt + 1 - chunk * 8);
    const int t0k = chunk * 8;

    const long gs_q = (long)(b * 256 + qt * 4 + wave);
    const unsigned short* qb = Qf + gs_q * 1024 + lane * 8;
    const bf16x8 qf0 = *(const bf16x8*)qb;
    const bf16x8 qf1 = *(const bf16x8*)(qb + 512);

    f32x4 o_acc[4];
    f32x4 l_vec = (f32x4){0.f, 0.f, 0.f, 0.f};
#pragma unroll
    for (int hf = 0; hf < 4; ++hf) o_acc[hf] = (f32x4){0.f, 0.f, 0.f, 0.f};

    // preload tile 0
    bf16x8 kf[8], vf[8];
    {
        const unsigned short* kb = Kf + (long)(b * 256 + t0k * 4) * 1024 + lane * 8;
        const unsigned short* vb = Vf + (long)(b * 64 + t0k) * 4096 + lane * 8;
#pragma unroll
        for (int ct = 0; ct < 4; ++ct) {
            kf[ct * 2 + 0] = *(const bf16x8*)(kb + ct * 1024);
            kf[ct * 2 + 1] = *(const bf16x8*)(kb + ct * 1024 + 512);
        }
#pragma unroll
        for (int f = 0; f < 8; ++f) vf[f] = *(const bf16x8*)(vb + f * 512);
    }

#pragma unroll 2
    for (int t = 0; t < ntt; ++t) {
        const int kc = t0k + t;
        const bool more = (t + 1 < ntt);
        const unsigned short* kbn = Kf + (long)(b * 256 + (kc + 1) * 4) * 1024 + lane * 8;
        const unsigned short* vbn = Vf + (long)(b * 64 + kc + 1) * 4096 + lane * 8;
        unsigned short* pw = Ps + ((wave << 1) | (t & 1)) * 16 * PSP;  // dbuf

        // S^T = K Q^T : (s = kc*64 + ct*16 + quad*4 + r, q = lane15)
        f32x4 st[4];
#pragma unroll
        for (int ct = 0; ct < 4; ++ct) {
            f32x4 zz = (f32x4){0.f, 0.f, 0.f, 0.f};
            zz = mfma16(kf[ct * 2 + 0], qf0, zz);
            zz = mfma16(kf[ct * 2 + 1], qf1, zz);
            st[ct] = zz;
        }

        if (more) {
#pragma unroll
            for (int ct = 0; ct < 4; ++ct) {
                kf[ct * 2 + 0] = *(const bf16x8*)(kbn + ct * 1024);
                kf[ct * 2 + 1] = *(const bf16x8*)(kbn + ct * 1024 + 512);
            }
        }

        if (kc == qt) {
            const int qg = wave * 16 + lane15;
#pragma unroll
            for (int ct = 0; ct < 4; ++ct) {
                const int sb = ct * 16 + quad * 4;
#pragma unroll
                for (int r = 0; r < 4; ++r)
                    if (sb + r > qg) st[ct][r] = -3.0e38f;
            }
        }

        // fixed-max softmax (exp2 domain); vector l accumulator
#pragma unroll
        for (int ct = 0; ct < 4; ++ct) {
#pragma unroll
            for (int r = 0; r < 4; ++r)
                st[ct][r] = __builtin_amdgcn_exp2f(st[ct][r]);
            l_vec += st[ct];
        }

        // pack P (s-contiguous in regs) -> LDS [q][s]
#pragma unroll
        for (int ct = 0; ct < 4; ++ct) {
            unsigned int w0 = pkbf(st[ct][1], st[ct][0]);
            unsigned int w1 = pkbf(st[ct][3], st[ct][2]);
            *(uint2*)&pw[lane15 * PSP + ct * 16 + quad * 4] = make_uint2(w0, w1);
        }

        bf16x8 pa0 = *(const bf16x8*)&pw[lane15 * PSP + quad * 8];
        bf16x8 pa1 = *(const bf16x8*)&pw[lane15 * PSP + 32 + quad * 8];
#pragma unroll
        for (int hf = 0; hf < 4; ++hf) {
            o_acc[hf] = mfma16(pa0, vf[hf * 2 + 0], o_acc[hf]);
            o_acc[hf] = mfma16(pa1, vf[hf * 2 + 1], o_acc[hf]);
        }

        if (more) {
#pragma unroll
            for (int f = 0; f < 8; ++f) vf[f] = *(const bf16x8*)(vbn + f * 512);
        }
    }

    // l: fold vector lanes then sum over the 4 quads holding each q
    float l_acc = (l_vec[0] + l_vec[1]) + (l_vec[2] + l_vec[3]);
    l_acc += __shfl_xor(l_acc, 16);
    l_acc += __shfl_xor(l_acc, 32);

    if ((qt >> 3) == 0) {
        // single-chunk q tile: normalize and write out directly
        float linv[4];
#pragma unroll
        for (int r = 0; r < 4; ++r) linv[r] = 1.0f / __shfl(l_acc, quad * 4 + r);
        float* o = out + ((long)b * T_ + qt * 64 + wave * 16) * H_;
#pragma unroll
        for (int hf = 0; hf < 4; ++hf)
#pragma unroll
            for (int r = 0; r < 4; ++r)
                o[(quad * 4 + r) * H_ + hf * 16 + lane15] = o_acc[hf][r] * linv[r];
    } else {
        const long pbase = ((long)(b * 64 + qt) * 8 + chunk) * 64;
        if (quad == 0) lp[pbase + wave * 16 + lane15] = l_acc;
        unsigned short* op = Opb + (pbase + wave * 16) * 64;
#pragma unroll
        for (int hf = 0; hf < 4; ++hf)
#pragma unroll
            for (int r = 0; r < 4; ++r)
                op[(quad * 4 + r) * 64 + hf * 16 + lane15] = f2bf(o_acc[hf][r]);
    }
}

// ---------------------------------------------------------------------------
// Kernel 3: merge bf16 chunk partials for qt in [8, 64). Block = (qt-8, b).
// ---------------------------------------------------------------------------
__global__ __launch_bounds__(256) void merge_kernel(const unsigned short* __restrict__ Opb,
                                                    const float* __restrict__ lp,
                                                    float* __restrict__ out) {
    const int qt = 8 + blockIdx.x;
    const int b = blockIdx.y;
    const int nc = 1 + (qt >> 3);   // 2..8
    const int tid = threadIdx.x;
    const int row = tid >> 2;
    const int seg = (tid & 3) << 4;  // 16 h per thread

    const long base = (long)(b * 64 + qt) * 8;
    float l = 0.f;
    f32x4 a[4];
#pragma unroll
    for (int j = 0; j < 4; ++j) a[j] = (f32x4){0.f, 0.f, 0.f, 0.f};

    for (int c = 0; c < nc; ++c) {
        l += lp[(base + c) * 64 + row];
        const unsigned short* op = Opb + ((base + c) * 64 + row) * 64 + seg;
        uint4 d0 = *(const uint4*)(op);
        uint4 d1 = *(const uint4*)(op + 8);
        a[0][0] += bf2f_lo(d0.x); a[0][1] += bf2f_hi(d0.x);
        a[0][2] += bf2f_lo(d0.y); a[0][3] += bf2f_hi(d0.y);
        a[1][0] += bf2f_lo(d0.z); a[1][1] += bf2f_hi(d0.z);
        a[1][2] += bf2f_lo(d0.w); a[1][3] += bf2f_hi(d0.w);
        a[2][0] += bf2f_lo(d1.x); a[2][1] += bf2f_hi(d1.x);
        a[2][2] += bf2f_lo(d1.y); a[2][3] += bf2f_hi(d1.y);
        a[3][0] += bf2f_lo(d1.z); a[3][1] += bf2f_hi(d1.z);
        a[3][2] += bf2f_lo(d1.w); a[3][3] += bf2f_hi(d1.w);
    }
    const float inv = 1.0f / l;
    float* o = out + ((long)b * T_ + qt * 64 + row) * H_ + seg;
#pragma unroll
    for (int j = 0; j < 4; ++j) *(f32x4*)(o + j * 4) = a[j] * inv;
}

// ---------------------------------------------------------------------------
extern "C" void kernel_launch(void* const* d_in, const int* in_sizes, int n_in,
                              void* d_out, int out_size, void* d_ws, size_t ws_size,
                              hipStream_t stream) {
    const float* x  = (const float*)d_in[0];
    const float* Wk = (const float*)d_in[1];
    const float* Wq = (const float*)d_in[2];
    const float* Wv = (const float*)d_in[3];
    float* out = (float*)d_out;

    char* ws = (char*)d_ws;
    unsigned short* Kf  = (unsigned short*)(ws);                // 2 MB
    unsigned short* Qf  = (unsigned short*)(ws + (2u << 20));   // 2 MB
    unsigned short* Vf  = (unsigned short*)(ws + (4u << 20));   // 2 MB
    unsigned short* Wtp = (unsigned short*)(ws + (6u << 20));   // 192 KB
    unsigned short* Opb = (unsigned short*)(ws + (8u << 20));   // 16.8 MB
    float* lp = (float*)(ws + (26u << 20));                     // 512 KB

    wt_kernel<<<384, 256, 0, stream>>>(Wk, Wq, Wv, Wtp);
    proj_kernel<<<BT / 32, 256, 0, stream>>>(x, Wtp, Kf, Qf, Vf);
    attn_kernel<<<dim3(288, B_), 256, 0, stream>>>(Qf, Kf, Vf, Opb, lp, out);
    merge_kernel<<<dim3(56, B_), 256, 0, stream>>>(Opb, lp, out);
}